// Round 6
// baseline (854.770 us; speedup 1.0000x reference)
//
#include <hip/hip_runtime.h>
#include <stdint.h>

#define NNODES 100000
#define NEDGES 600000
#define NGRAPH 256
#define KCH 5
#define F1 16
#define O1 64
#define F2 128
#define O2 256
#define FT1 (KCH * F1) /* 80  */
#define FT2 (KCH * F2) /* 640: K-extent of W2 (B packing) */
#define STR2 512       /* layer-2 node buffer stride: chunks 0..3 only (Tx4 never hits HBM) */
#define KSTEPS 20      /* 640/32 */
#define KS1 3          /* ceil(80/32) for layer-1 MFMA GEMM (K padded to 96) */
#define LROW 40        /* GEMM staging row stride in ushorts: 64 B + 16 B pad */
#define LROWD 68       /* Tx4 LDS row stride in dwords: 64 + 4 pad */
#define NXCD 8         /* MI355X chiplets; blockIdx round-robins across them */

typedef unsigned short ushort_t;
typedef __attribute__((ext_vector_type(8))) short bf16x8;
typedef __attribute__((ext_vector_type(4))) float f32x4;

__device__ __forceinline__ float bflo(unsigned int u) {
    union { unsigned int u; float f; } v; v.u = u << 16; return v.f;
}
__device__ __forceinline__ float bfhi(unsigned int u) {
    union { unsigned int u; float f; } v; v.u = u & 0xFFFF0000u; return v.f;
}
__device__ __forceinline__ unsigned int f2bf(float f) {
    union { float f; unsigned int u; } v; v.f = f;
    return (v.u + 0x7FFFu + ((v.u >> 16) & 1u)) >> 16;  // RNE
}
__device__ __forceinline__ unsigned int pack2(float lo, float hi) {
    return (f2bf(hi) << 16) | f2bf(lo);
}

// -------------------- CSR build --------------------

__global__ void k_count(const int* __restrict__ src, const int* __restrict__ dst,
                        int* __restrict__ cntDst, int* __restrict__ cntSrc, int E) {
    int e = blockIdx.x * 256 + threadIdx.x;
    if (e < E) {
        atomicAdd(&cntDst[dst[e]], 1);
        atomicAdd(&cntSrc[src[e]], 1);
    }
}

__global__ void k_dinv(const int* __restrict__ cntDst, const int* __restrict__ cntSrc,
                       float* __restrict__ dinvF, float* __restrict__ dinvR, int n) {
    int i = blockIdx.x * 256 + threadIdx.x;
    if (i < n) {
        int cs = cntSrc[i], cd = cntDst[i];
        dinvF[i] = cs > 0 ? rsqrtf((float)cs) : 0.f;  // deg over src -> fwd norm
        dinvR[i] = cd > 0 ? rsqrtf((float)cd) : 0.f;  // deg over dst -> rev norm
    }
}

// merged exclusive scans (fwd+rev in one launch), 512 elems/block-half
__global__ void k_scan1m(const int* __restrict__ inF, int* __restrict__ outF,
                         int* __restrict__ bsF,
                         const int* __restrict__ inR, int* __restrict__ outR,
                         int* __restrict__ bsR, int n, int NB) {
    __shared__ int a[512];
    __shared__ int s[256];
    int b = blockIdx.x;
    const int* in; int* out; int* bs; int lb;
    if (b < NB) { in = inF; out = outF; bs = bsF; lb = b; }
    else        { in = inR; out = outR; bs = bsR; lb = b - NB; }
    int t = threadIdx.x;
    int base = lb * 512;
    a[t]       = (base + t < n)       ? in[base + t]       : 0;
    a[t + 256] = (base + t + 256 < n) ? in[base + t + 256] : 0;
    __syncthreads();
    s[t] = a[2 * t] + a[2 * t + 1];
    __syncthreads();
    for (int off = 1; off < 256; off <<= 1) {
        int v = (t >= off) ? s[t - off] : 0;
        __syncthreads();
        s[t] += v;
        __syncthreads();
    }
    int ep = (t > 0) ? s[t - 1] : 0;  // exclusive over pairs
    if (base + 2 * t < n)     out[base + 2 * t]     = ep;
    if (base + 2 * t + 1 < n) out[base + 2 * t + 1] = ep + a[2 * t];
    if (t == 255) bs[lb] = s[255];
}

__global__ void k_scan2m(int* __restrict__ bsF, int* __restrict__ bsR, int nb) {
    __shared__ int s[256];
    int* bs = (blockIdx.x == 0) ? bsF : bsR;
    int t = threadIdx.x;
    s[t] = (t < nb) ? bs[t] : 0;
    __syncthreads();
    for (int off = 1; off < 256; off <<= 1) {
        int v = (t >= off) ? s[t - off] : 0;
        __syncthreads();
        s[t] += v;
        __syncthreads();
    }
    if (t < nb) bs[t] = (t > 0) ? s[t - 1] : 0;
}

// adds block prefix, mirrors into cur (replaces D2D memcpys), writes off[n]=E tail
__global__ void k_scan3m(int* __restrict__ outF, int* __restrict__ curF,
                         const int* __restrict__ bsF,
                         int* __restrict__ outR, int* __restrict__ curR,
                         const int* __restrict__ bsR, int n, int E, int NB) {
    int b = blockIdx.x;
    int* out; int* cur; const int* bs; int lb;
    if (b < NB) { out = outF; cur = curF; bs = bsF; lb = b; }
    else        { out = outR; cur = curR; bs = bsR; lb = b - NB; }
    int i = lb * 512 + threadIdx.x;
    int add = bs[lb];
    if (i < n)       { int v = out[i] + add;       out[i] = v;       cur[i] = v; }
    if (i + 256 < n) { int v = out[i + 256] + add; out[i + 256] = v; cur[i + 256] = v; }
    if (lb == 0 && threadIdx.x == 0) out[n] = E;
}

// XCD-localized scatter: blocks with (blockIdx%8 == c) only emit records for
// node-chunk c; with round-robin blockIdx->XCD dispatch each CSR chunk is
// written by a single XCD, so lines coalesce in that L2 and write back once
// (naive version had 8x write amplification: 79.5 MB for a 9.6 MB payload).
__global__ void k_scatter(const int* __restrict__ src, const int* __restrict__ dst,
                          const float* __restrict__ dinvF, const float* __restrict__ dinvR,
                          int* __restrict__ curF, int* __restrict__ curR,
                          int2* __restrict__ edF, int2* __restrict__ edR, int E,
                          int chunk) {
    int c = blockIdx.x & (NXCD - 1);        // node-chunk (== target XCD)
    int sb = blockIdx.x >> 3;               // slice index within the chunk's blocks
    int slices = gridDim.x >> 3;
    int lo = c * chunk, hi = lo + chunk;
    for (int e = sb * 256 + threadIdx.x; e < E; e += slices * 256) {
        int s = src[e], d = dst[e];
        if (d >= lo && d < hi) {
            int p = atomicAdd(&curF[d], 1);
            float wf = -dinvF[s] * dinvF[d];
            edF[p] = make_int2(s, __float_as_int(wf));
        }
        if (s >= lo && s < hi) {
            int q = atomicAdd(&curR[s], 1);
            float wr = -dinvR[s] * dinvR[d];
            edR[q] = make_int2(d, __float_as_int(wr));
        }
    }
}

__global__ void k_gstart(const int* __restrict__ batch, int* __restrict__ gstart, int n) {
    int g = blockIdx.x * 64 + threadIdx.x;
    if (g > NGRAPH) return;
    if (g == NGRAPH) { gstart[g] = n; return; }
    int lo = 0, hi = n;
    while (lo < hi) {
        int mid = (lo + hi) >> 1;
        if (batch[mid] < g) lo = mid + 1; else hi = mid;
    }
    gstart[g] = lo;
}

// -------------------- compute --------------------

// copy x into interleaved fp32 Tx chunk 0 AND dense bf16 gather mirror
__global__ void k_copyx(const float* __restrict__ x, float* __restrict__ Tx,
                        ushort_t* __restrict__ TxB, int n) {
    int tid = blockIdx.x * 256 + threadIdx.x;
    int r = tid >> 2, c = tid & 3;
    if (r < n) {
        float4 v = *(const float4*)(x + (size_t)r * 16 + c * 4);
        *(float4*)(Tx + (size_t)r * FT1 + c * 4) = v;
        uint2 b;
        b.x = pack2(v.x, v.y);
        b.y = pack2(v.z, v.w);
        *(uint2*)(TxB + (size_t)r * F1 + c * 4) = b;
    }
}

// fp32 SpMM (layer 1, F=16), bf16 gather source: HinB is a DENSE [n,16] bf16
// mirror (3.2 MB -> L2-resident; halves gather bytes 64B->32B/edge). fp32
// recursion state (Tx0, Hout) unaffected; gemm1 quantizes to bf16 anyway.
__global__ void k_spmm_f32(const ushort_t* __restrict__ HinB, float* __restrict__ Hout,
                           ushort_t* __restrict__ HoutB,
                           const float* __restrict__ Tx0,
                           const int* __restrict__ off, const int2* __restrict__ ed,
                           int n) {
    int tid = blockIdx.x * 256 + threadIdx.x;
    int r = tid >> 2, c = tid & 3;
    if (r >= n) return;
    int j0 = off[r], j1 = off[r + 1];
    float4 s = {0.f, 0.f, 0.f, 0.f};
    int j = j0;
    for (; j + 4 <= j1; j += 4) {
        int2 e0 = ed[j], e1 = ed[j + 1], e2 = ed[j + 2], e3 = ed[j + 3];
        float wa = __int_as_float(e0.y), wb = __int_as_float(e1.y);
        float wc = __int_as_float(e2.y), wd = __int_as_float(e3.y);
        const uint2 h0 = *(const uint2*)(HinB + (size_t)e0.x * F1 + c * 4);
        const uint2 h1 = *(const uint2*)(HinB + (size_t)e1.x * F1 + c * 4);
        const uint2 h2 = *(const uint2*)(HinB + (size_t)e2.x * F1 + c * 4);
        const uint2 h3 = *(const uint2*)(HinB + (size_t)e3.x * F1 + c * 4);
        s.x = fmaf(wa, bflo(h0.x), s.x); s.y = fmaf(wa, bfhi(h0.x), s.y);
        s.z = fmaf(wa, bflo(h0.y), s.z); s.w = fmaf(wa, bfhi(h0.y), s.w);
        s.x = fmaf(wb, bflo(h1.x), s.x); s.y = fmaf(wb, bfhi(h1.x), s.y);
        s.z = fmaf(wb, bflo(h1.y), s.z); s.w = fmaf(wb, bfhi(h1.y), s.w);
        s.x = fmaf(wc, bflo(h2.x), s.x); s.y = fmaf(wc, bfhi(h2.x), s.y);
        s.z = fmaf(wc, bflo(h2.y), s.z); s.w = fmaf(wc, bfhi(h2.y), s.w);
        s.x = fmaf(wd, bflo(h3.x), s.x); s.y = fmaf(wd, bfhi(h3.x), s.y);
        s.z = fmaf(wd, bflo(h3.y), s.z); s.w = fmaf(wd, bfhi(h3.y), s.w);
    }
    for (; j < j1; ++j) {
        int2 e = ed[j];
        float w2 = __int_as_float(e.y);
        const uint2 h = *(const uint2*)(HinB + (size_t)e.x * F1 + c * 4);
        s.x = fmaf(w2, bflo(h.x), s.x); s.y = fmaf(w2, bfhi(h.x), s.y);
        s.z = fmaf(w2, bflo(h.y), s.z); s.w = fmaf(w2, bfhi(h.y), s.w);
    }
    float4 o;
    if (Tx0) {
        const float4 t0 = *(const float4*)(Tx0 + (size_t)r * FT1 + c * 4);
        o.x = 2.f * s.x - t0.x; o.y = 2.f * s.y - t0.y;
        o.z = 2.f * s.z - t0.z; o.w = 2.f * s.w - t0.w;
    } else {
        o = s;
    }
    *(float4*)(Hout + (size_t)r * FT1 + c * 4) = o;
    if (HoutB) {
        uint2 b;
        b.x = pack2(o.x, o.y);
        b.y = pack2(o.z, o.w);
        *(uint2*)(HoutB + (size_t)r * F1 + c * 4) = b;
    }
}

// bf16 SpMM (layer 2, F=128), r1-proven loop: one wave per row, scalar edge
// stream, unconditional full 8-slot blocks + wave-uniform-guarded tail.
// (r4's software pipelining regressed the cold-path total; reverted.)
__global__ void k_spmm_bf(const ushort_t* __restrict__ Hin, ushort_t* __restrict__ Hout,
                          const ushort_t* __restrict__ Tx0,
                          const int* __restrict__ off, const int2* __restrict__ ed,
                          int n) {
    int r = blockIdx.x * 4 + (threadIdx.x >> 6);
    r = __builtin_amdgcn_readfirstlane(r);   // wave-uniform -> scalar edge loads
    int c = threadIdx.x & 63;
    if (r >= n) return;
    int j0 = __builtin_amdgcn_readfirstlane(off[r]);
    int j1 = __builtin_amdgcn_readfirstlane(off[r + 1]);
    float s0 = 0.f, s1 = 0.f;
    int j = j0;
    int jfull = j0 + ((j1 - j0) & ~7);
    for (; j < jfull; j += 8) {
        float w[8];
        unsigned int h[8];
#pragma unroll
        for (int sl = 0; sl < 8; ++sl) {
            int2 e = ed[j + sl];
            w[sl] = __int_as_float(e.y);
            h[sl] = *(const unsigned int*)(Hin + (size_t)e.x * STR2 + c * 2);
        }
#pragma unroll
        for (int sl = 0; sl < 8; ++sl) {
            s0 = fmaf(bflo(h[sl]), w[sl], s0);
            s1 = fmaf(bfhi(h[sl]), w[sl], s1);
        }
    }
    int rem = j1 - j;  // 0..7, wave-uniform
    if (rem) {
        float w[8];
        unsigned int h[8];
#pragma unroll
        for (int sl = 0; sl < 8; ++sl) {
            w[sl] = 0.f; h[sl] = 0u;
            if (sl < rem) {  // uniform branch: s_cbranch, no divergence
                int2 e = ed[j + sl];
                w[sl] = __int_as_float(e.y);
                h[sl] = *(const unsigned int*)(Hin + (size_t)e.x * STR2 + c * 2);
            }
        }
#pragma unroll
        for (int sl = 0; sl < 8; ++sl) {
            s0 = fmaf(bflo(h[sl]), w[sl], s0);
            s1 = fmaf(bfhi(h[sl]), w[sl], s1);
        }
    }
    if (Tx0) {
        unsigned int t0 = *(const unsigned int*)(Tx0 + (size_t)r * STR2 + c * 2);
        s0 = 2.f * s0 - bflo(t0);
        s1 = 2.f * s1 - bfhi(t0);
    }
    *(unsigned int*)(Hout + (size_t)r * STR2 + c * 2) = pack2(s0, s1);
}

// merged pack W [80,64] fp32 -> bf16 MFMA B-frags (both directions), K 80->96
__global__ void k_packW1m(const float* __restrict__ WF, ushort_t* __restrict__ BpF_,
                          const float* __restrict__ WR, ushort_t* __restrict__ BpR_) {
    int b = blockIdx.x;
    const float* W = (b < 3) ? WF : WR;
    ushort_t* Bp = (b < 3) ? BpF_ : BpR_;
    int tid = ((b < 3) ? b : b - 3) * 256 + threadIdx.x;
    if (tid >= 4 * KS1 * 64) return;
    int lane = tid & 63;
    int ks = (tid >> 6) % KS1;
    int nt = tid / (64 * KS1);
    int k0 = ks * 32 + (lane >> 4) * 8;
    int ncol = nt * 16 + (lane & 15);
    float v[8];
#pragma unroll
    for (int j = 0; j < 8; ++j) {
        int k = k0 + j;
        v[j] = (k < FT1) ? W[(size_t)k * O1 + ncol] : 0.f;
    }
    uint4 o;
    o.x = pack2(v[0], v[1]); o.y = pack2(v[2], v[3]);
    o.z = pack2(v[4], v[5]); o.w = pack2(v[6], v[7]);
    *(uint4*)(Bp + (size_t)tid * 8) = o;
}

// layer-1 MFMA GEMM: A fp32 [n,80] (k-padded reads to 96) x Bp bf16 -> bf16 out
// slice (ld=STR2), bias+relu. Block = 4 waves; wave w: rows blk*64+w*16..+16.
__global__ __launch_bounds__(256) void k_gemm1_mfma(
    const float* __restrict__ A, const ushort_t* __restrict__ Bp,
    const float* __restrict__ bias, ushort_t* __restrict__ out, int n) {
    int lane = threadIdx.x & 63;
    int wvi = threadIdx.x >> 6;
    int mrow = lane & 15;
    int quad = lane >> 4;
    int m0w = blockIdx.x * 64 + wvi * 16;
    int row = m0w + mrow;
    int rowc = row < n ? row : n - 1;  // clamp loads; stores masked below
    const float* Ar = A + (size_t)rowc * FT1 + quad * 8;

    f32x4 acc[4] = {};
#pragma unroll
    for (int ks = 0; ks < KS1; ++ks) {
        float4 a0 = *(const float4*)(Ar + ks * 32);
        float4 a1 = *(const float4*)(Ar + ks * 32 + 4);
        union { bf16x8 v; unsigned int u[4]; } ua;
        ua.u[0] = pack2(a0.x, a0.y);
        ua.u[1] = pack2(a0.z, a0.w);
        ua.u[2] = pack2(a1.x, a1.y);
        ua.u[3] = pack2(a1.z, a1.w);
#pragma unroll
        for (int nf = 0; nf < 4; ++nf) {
            bf16x8 bfr = *(const bf16x8*)(Bp + ((size_t)(nf * KS1 + ks) * 64 + lane) * 8);
            acc[nf] = __builtin_amdgcn_mfma_f32_16x16x32_bf16(ua.v, bfr, acc[nf], 0, 0, 0);
        }
    }
    // C/D layout: col = nf*16 + (lane&15), row = m0w + quad*4 + reg
#pragma unroll
    for (int nf = 0; nf < 4; ++nf) {
        float bb = bias[nf * 16 + mrow];
#pragma unroll
        for (int reg = 0; reg < 4; ++reg) {
            int orow = m0w + quad * 4 + reg;
            if (orow < n)
                out[(size_t)orow * STR2 + nf * 16 + mrow] =
                    (ushort_t)f2bf(fmaxf(acc[nf][reg] + bb, 0.f));
        }
    }
}

// merged pack W [640,256] fp32 -> bf16 MFMA B-fragment layout (both directions)
__global__ void k_packWm(const float* __restrict__ WF, ushort_t* __restrict__ BpF_,
                         const float* __restrict__ WR, ushort_t* __restrict__ BpR_) {
    int b = blockIdx.x;
    const float* W = (b < 80) ? WF : WR;
    ushort_t* Bp = (b < 80) ? BpF_ : BpR_;
    int tid = ((b < 80) ? b : b - 80) * 256 + threadIdx.x;
    if (tid >= 16 * KSTEPS * 64) return;
    int lane = tid & 63;
    int ks = (tid >> 6) % KSTEPS;
    int nt = tid / (64 * KSTEPS);
    int k0 = ks * 32 + (lane >> 4) * 8;
    int ncol = nt * 16 + (lane & 15);
    float v[8];
#pragma unroll
    for (int j = 0; j < 8; ++j) v[j] = W[(size_t)(k0 + j) * O2 + ncol];
    uint4 o;
    o.x = pack2(v[0], v[1]); o.y = pack2(v[2], v[3]);
    o.z = pack2(v[4], v[5]); o.w = pack2(v[6], v[7]);
    *(uint4*)(Bp + (size_t)tid * 8) = o;
}

// FUSED 4th-SpMM + layer-2 GEMM. Phase 1: each wave computes 16 Tx4 rows
// (r1 gather loop) into LDS only -- Tx4 never touches HBM (-25.6 MB write and
// -25.6 MB of the GEMM A-stream per direction). Phase 2: exact r1 GEMM
// (64-row block, 4 waves, per-K-step double-buffered staging) with K-steps
// 0..15 staged from global chunks 0..3 and K-steps 16..19 read from the LDS
// Tx4 rows. ReLU applies to the full-K sum in the epilogue (chunk-incremental
// pooling would be wrong). Gather-phase blocks overlap GEMM-phase blocks
// per CU (MFMA + VMEM pipes both fed).
__global__ __launch_bounds__(256) void k_spmm4_gemm(
    const ushort_t* __restrict__ Hin,   // Tx3 (gather source)
    const ushort_t* __restrict__ Txc,   // Tx2 (recursion correction)
    const int* __restrict__ off, const int2* __restrict__ ed,
    const ushort_t* __restrict__ A,     // chunks 0..3 base (ld STR2)
    const ushort_t* __restrict__ Bp,
    const float* __restrict__ bias, float* __restrict__ pooled, int colofs,
    const int* __restrict__ batch, int n) {
    __shared__ ushort_t lds[2][64 * LROW];   // 10240 B staging (ksteps 0..15)
    __shared__ unsigned int a4[64 * LROWD];  // 17408 B Tx4 rows (dwords)

    int lane = threadIdx.x & 63;
    int wv = threadIdx.x >> 6;
    int m0 = blockIdx.x * 64;

    // ---- phase 1: Tx4 rows m0 + wv*16 + i -> a4 ----
    for (int i = 0; i < 16; ++i) {
        int r = m0 + wv * 16 + i;   // wave-uniform
        float s0 = 0.f, s1 = 0.f;
        if (r < n) {
            int j0 = __builtin_amdgcn_readfirstlane(off[r]);
            int j1 = __builtin_amdgcn_readfirstlane(off[r + 1]);
            int j = j0;
            int jfull = j0 + ((j1 - j0) & ~7);
            for (; j < jfull; j += 8) {
                float w[8];
                unsigned int h[8];
#pragma unroll
                for (int sl = 0; sl < 8; ++sl) {
                    int2 e = ed[j + sl];
                    w[sl] = __int_as_float(e.y);
                    h[sl] = *(const unsigned int*)(Hin + (size_t)e.x * STR2 + lane * 2);
                }
#pragma unroll
                for (int sl = 0; sl < 8; ++sl) {
                    s0 = fmaf(bflo(h[sl]), w[sl], s0);
                    s1 = fmaf(bfhi(h[sl]), w[sl], s1);
                }
            }
            int rem = j1 - j;
            if (rem) {
                float w[8];
                unsigned int h[8];
#pragma unroll
                for (int sl = 0; sl < 8; ++sl) {
                    w[sl] = 0.f; h[sl] = 0u;
                    if (sl < rem) {
                        int2 e = ed[j + sl];
                        w[sl] = __int_as_float(e.y);
                        h[sl] = *(const unsigned int*)(Hin + (size_t)e.x * STR2 + lane * 2);
                    }
                }
#pragma unroll
                for (int sl = 0; sl < 8; ++sl) {
                    s0 = fmaf(bflo(h[sl]), w[sl], s0);
                    s1 = fmaf(bfhi(h[sl]), w[sl], s1);
                }
            }
            unsigned int t0 = *(const unsigned int*)(Txc + (size_t)r * STR2 + lane * 2);
            s0 = 2.f * s0 - bflo(t0);
            s1 = 2.f * s1 - bfhi(t0);
        }
        a4[(wv * 16 + i) * LROWD + lane] = pack2(s0, s1);
    }
    __syncthreads();  // a4 complete for all waves

    // ---- phase 2: GEMM (r1 structure) ----
    int mrow = lane & 15;
    int quad = lane >> 4;
    int srow = threadIdx.x >> 2;  // staging row 0..63
    int sc = threadIdx.x & 3;     // staging 16B chunk 0..3

    const ushort_t* Ag = A + (size_t)(m0 + srow) * STR2 + sc * 8;  // buffer padded past n
    const ushort_t* Bbase = Bp + ((size_t)(wv * 4) * KSTEPS * 64 + lane) * 8;
    int sidx = srow * LROW + sc * 8;

    f32x4 acc[4][4] = {};  // [mfrag][nfrag]
    uint4 nxt;
    bf16x8 bcur[4], bnxt[4];
    {
        uint4 c0 = *(const uint4*)(Ag);
        *(uint4*)&lds[0][sidx] = c0;
        nxt = *(const uint4*)(Ag + 32);
#pragma unroll
        for (int nf = 0; nf < 4; ++nf)
            bcur[nf] = *(const bf16x8*)(Bbase + ((size_t)nf * KSTEPS) * 512);
    }

    for (int ks = 0; ks < KSTEPS; ++ks) {
        __syncthreads();
        // stage ks+1 (global chunks only: ks+1 < 16)
        if (ks + 1 < 16)
            *(uint4*)&lds[(ks + 1) & 1][sidx] = nxt;
        if (ks + 2 < 16)
            nxt = *(const uint4*)(Ag + (ks + 2) * 32);
        if (ks + 1 < KSTEPS) {
#pragma unroll
            for (int nf = 0; nf < 4; ++nf)
                bnxt[nf] = *(const bf16x8*)(Bbase + ((size_t)nf * KSTEPS + ks + 1) * 512);
        }
        bf16x8 af[4];
        if (ks < 16) {
            const ushort_t* lbuf = &lds[ks & 1][0];
#pragma unroll
            for (int mf = 0; mf < 4; ++mf)
                af[mf] = *(const bf16x8*)(lbuf + (mf * 16 + mrow) * LROW + quad * 8);
        } else {
            int kk = ks - 16;
#pragma unroll
            for (int mf = 0; mf < 4; ++mf)
                af[mf] = *(const bf16x8*)(a4 + (size_t)(mf * 16 + mrow) * LROWD +
                                          kk * 16 + quad * 4);
        }
#pragma unroll
        for (int mf = 0; mf < 4; ++mf)
#pragma unroll
            for (int nf = 0; nf < 4; ++nf)
                acc[mf][nf] = __builtin_amdgcn_mfma_f32_16x16x32_bf16(
                    af[mf], bcur[nf], acc[mf][nf], 0, 0, 0);
#pragma unroll
        for (int nf = 0; nf < 4; ++nf) bcur[nf] = bnxt[nf];
    }

    // epilogue: C/D layout col=lane&15, row=quad*4+reg; pool into pooled[g*512+colofs+col]
    float bcol[4];
#pragma unroll
    for (int nf = 0; nf < 4; ++nf) bcol[nf] = bias[wv * 64 + nf * 16 + mrow];

#pragma unroll
    for (int mf = 0; mf < 4; ++mf) {
        int t0 = m0 + mf * 16;
        if (t0 >= n) break;
        int te = (t0 + 15 < n) ? t0 + 15 : n - 1;
        int r0 = t0 + quad * 4;
        if (batch[t0] == batch[te]) {
            // whole 16-row tile in one graph: cross-quad reduce, 1 atomic / (nf, col)
            int g = batch[t0];
#pragma unroll
            for (int nf = 0; nf < 4; ++nf) {
                float s = 0.f;
#pragma unroll
                for (int reg = 0; reg < 4; ++reg) {
                    float v = fmaxf(acc[mf][nf][reg] + bcol[nf], 0.f);
                    if (r0 + reg < n) s += v;
                }
                s += __shfl_xor(s, 16, 64);
                s += __shfl_xor(s, 32, 64);
                if (quad == 0)
                    atomicAdd(pooled + (size_t)g * 512 + colofs + wv * 64 + nf * 16 + mrow, s);
            }
        } else {
            // boundary tile: per-lane run merge over 4 consecutive rows
            int gb[4];
#pragma unroll
            for (int reg = 0; reg < 4; ++reg)
                gb[reg] = batch[(r0 + reg < n) ? r0 + reg : n - 1];
#pragma unroll
            for (int nf = 0; nf < 4; ++nf) {
                int col = colofs + wv * 64 + nf * 16 + mrow;
                float run = 0.f;
                int g = gb[0];
                bool any = false;
#pragma unroll
                for (int reg = 0; reg < 4; ++reg) {
                    int row = r0 + reg;
                    if (row >= n) break;
                    float v = fmaxf(acc[mf][nf][reg] + bcol[nf], 0.f);
                    if (gb[reg] != g) {
                        atomicAdd(pooled + (size_t)g * 512 + col, run);
                        run = 0.f;
                        g = gb[reg];
                    }
                    run += v;
                    any = true;
                }
                if (any) atomicAdd(pooled + (size_t)g * 512 + col, run);
            }
        }
    }
}

// parallel logits: one block (64 threads) per graph; lane-strided dot + wave reduce
__global__ void k_logits(const float* __restrict__ pooled, const int* __restrict__ gstart,
                         const float* __restrict__ fcw, const float* __restrict__ fcb,
                         float* __restrict__ out) {
    int g = blockIdx.x;
    int l = threadIdx.x;  // 0..63
    int cnt = gstart[g + 1] - gstart[g];
    float inv = 1.f / (float)(cnt > 1 ? cnt : 1);
    float lg0 = 0.f, lg1 = 0.f, lg2 = 0.f, lg3 = 0.f;
    for (int f = l; f < 512; f += 64) {
        float p = pooled[g * 512 + f] * inv;
        const float4 wv4 = *(const float4*)(fcw + f * 4);
        lg0 = fmaf(p, wv4.x, lg0);
        lg1 = fmaf(p, wv4.y, lg1);
        lg2 = fmaf(p, wv4.z, lg2);
        lg3 = fmaf(p, wv4.w, lg3);
    }
#pragma unroll
    for (int o = 32; o > 0; o >>= 1) {
        lg0 += __shfl_down(lg0, o, 64);
        lg1 += __shfl_down(lg1, o, 64);
        lg2 += __shfl_down(lg2, o, 64);
        lg3 += __shfl_down(lg3, o, 64);
    }
    if (l == 0) {
        float lg[4] = {lg0 + fcb[0], lg1 + fcb[1], lg2 + fcb[2], lg3 + fcb[3]};
        float m = fmaxf(fmaxf(lg[0], lg[1]), fmaxf(lg[2], lg[3]));
        float s = 0.f;
#pragma unroll
        for (int o = 0; o < 4; ++o) s += expf(lg[o] - m);
        float lsum = logf(s);
#pragma unroll
        for (int o = 0; o < 4; ++o) out[g * 4 + o] = lg[o] - m - lsum;
    }
}

// -------------------- launch --------------------

extern "C" void kernel_launch(void* const* d_in, const int* in_sizes, int n_in,
                              void* d_out, int out_size, void* d_ws, size_t ws_size,
                              hipStream_t stream) {
    const float* x   = (const float*)d_in[0];
    const int* ei    = (const int*)d_in[1];
    const int* batch = (const int*)d_in[2];
    const float* W11 = (const float*)d_in[3];
    const float* b11 = (const float*)d_in[4];
    const float* W12 = (const float*)d_in[5];
    const float* b12 = (const float*)d_in[6];
    const float* W21 = (const float*)d_in[7];
    const float* b21 = (const float*)d_in[8];
    const float* W22 = (const float*)d_in[9];
    const float* b22 = (const float*)d_in[10];
    const float* fcw = (const float*)d_in[11];
    const float* fcb = (const float*)d_in[12];
    float* out = (float*)d_out;

    const int N = in_sizes[0] / F1;
    const int E = in_sizes[1] / 2;
    const int* src = ei;
    const int* dst = ei + E;

    char* w = (char*)d_ws;
    size_t pos = 0;
    auto alloc = [&](size_t bytes) -> void* {
        void* p = w + pos;
        pos += (bytes + 255) & ~(size_t)255;
        return p;
    };
    int* cur_f   = (int*)alloc((size_t)N * 4);
    int* cur_r   = (int*)alloc((size_t)N * 4);
    int* off_f   = (int*)alloc((size_t)(N + 1) * 4);
    int* off_r   = (int*)alloc((size_t)(N + 1) * 4);
    float* dinvF = (float*)alloc((size_t)N * 4);
    float* dinvR = (float*)alloc((size_t)N * 4);
    int2* ed_f   = (int2*)alloc((size_t)E * 8);
    int2* ed_r   = (int2*)alloc((size_t)E * 8);
    int* blks_f  = (int*)alloc(1024);
    int* blks_r  = (int*)alloc(1024);
    int* gstart  = (int*)alloc((NGRAPH + 1) * 4);
    float* pooled = (float*)alloc((size_t)NGRAPH * 512 * 4);
    ushort_t* BpF = (ushort_t*)alloc((size_t)FT2 * O2 * 2);      // 320 KB packed W21
    ushort_t* BpR = (ushort_t*)alloc((size_t)FT2 * O2 * 2);      // 320 KB packed W22
    ushort_t* Bp1F = (ushort_t*)alloc((size_t)4 * KS1 * 64 * 8 * 2);  // 12 KB packed W11
    ushort_t* Bp1R = (ushort_t*)alloc((size_t)4 * KS1 * 64 * 8 * 2);  // 12 KB packed W12
    float* TxAll1 = (float*)alloc(((size_t)N * FT1 + 256) * 4);  // 32 MB fp32 + k-pad
    ushort_t* TxB1 = (ushort_t*)alloc((size_t)KCH * N * F1 * 2); // 16 MB dense bf16 mirror
    ushort_t* TxAll2 = (ushort_t*)alloc((size_t)(N + 64) * STR2 * 2);  // 102 MB bf16 + pad
    // total ~165 MB

    (void)hipMemsetAsync(cur_f, 0, (size_t)N * 4, stream);
    (void)hipMemsetAsync(cur_r, 0, (size_t)N * 4, stream);
    (void)hipMemsetAsync(pooled, 0, (size_t)NGRAPH * 512 * 4, stream);

    int gE = (E + 255) / 256, gN = (N + 255) / 256;
    k_count<<<gE, 256, 0, stream>>>(src, dst, cur_f, cur_r, E);
    k_dinv<<<gN, 256, 0, stream>>>(cur_f, cur_r, dinvF, dinvR, N);

    int NB = (N + 511) / 512;
    k_scan1m<<<2 * NB, 256, 0, stream>>>(cur_f, off_f, blks_f, cur_r, off_r, blks_r, N, NB);
    k_scan2m<<<2, 256, 0, stream>>>(blks_f, blks_r, NB);
    k_scan3m<<<2 * NB, 256, 0, stream>>>(off_f, cur_f, blks_f, off_r, cur_r, blks_r, N, E, NB);
    // XCD-localized scatter: 8 chunk-replicas x 256 slice-blocks
    int chunk = (N + NXCD - 1) / NXCD;
    k_scatter<<<NXCD * 256, 256, 0, stream>>>(src, dst, dinvF, dinvR, cur_f, cur_r,
                                              ed_f, ed_r, E, chunk);
    k_gstart<<<5, 64, 0, stream>>>(batch, gstart, N);
    k_packWm<<<160, 256, 0, stream>>>(W21, BpF, W22, BpR);
    k_packW1m<<<6, 256, 0, stream>>>(W11, Bp1F, W12, Bp1R);

    // ---------------- layer 1 (fp32 Tx + dense bf16 gather mirror, F=16) ----
    k_copyx<<<(N * 4 + 255) / 256, 256, 0, stream>>>(x, TxAll1, TxB1, N);
    int gs1 = (N * 4 + 255) / 256;
    int gg1 = (N + 63) / 64;
    auto C1 = [&](int k) { return TxAll1 + k * F1; };
    auto B1 = [&](int k) { return TxB1 + (size_t)k * N * F1; };
    // fwd
    k_spmm_f32<<<gs1, 256, 0, stream>>>(B1(0), C1(1), B1(1), nullptr, off_f, ed_f, N);
    k_spmm_f32<<<gs1, 256, 0, stream>>>(B1(1), C1(2), B1(2), C1(0), off_f, ed_f, N);
    k_spmm_f32<<<gs1, 256, 0, stream>>>(B1(2), C1(3), B1(3), C1(1), off_f, ed_f, N);
    k_spmm_f32<<<gs1, 256, 0, stream>>>(B1(3), C1(4), nullptr, C1(2), off_f, ed_f, N);
    k_gemm1_mfma<<<gg1, 256, 0, stream>>>(TxAll1, Bp1F, b11, TxAll2, N);
    // rev (overwrites C1(1..4)/B1(1..3); chunk 0 = x preserved)
    k_spmm_f32<<<gs1, 256, 0, stream>>>(B1(0), C1(1), B1(1), nullptr, off_r, ed_r, N);
    k_spmm_f32<<<gs1, 256, 0, stream>>>(B1(1), C1(2), B1(2), C1(0), off_r, ed_r, N);
    k_spmm_f32<<<gs1, 256, 0, stream>>>(B1(2), C1(3), B1(3), C1(1), off_r, ed_r, N);
    k_spmm_f32<<<gs1, 256, 0, stream>>>(B1(3), C1(4), nullptr, C1(2), off_r, ed_r, N);
    k_gemm1_mfma<<<gg1, 256, 0, stream>>>(TxAll1, Bp1R, b12, TxAll2 + O1, N);

    // ---------------- layer 2 (bf16 Tx, F=128, chunks 0..3 materialized) ----
    int gs2 = (N + 3) / 4;
    auto C2 = [&](int k) { return TxAll2 + k * F2; };
    int gg = (N + 63) / 64;
    // fwd: 3 spmm + fused(spmm4 + GEMM + pool)
    k_spmm_bf<<<gs2, 256, 0, stream>>>(C2(0), C2(1), nullptr, off_f, ed_f, N);
    k_spmm_bf<<<gs2, 256, 0, stream>>>(C2(1), C2(2), C2(0), off_f, ed_f, N);
    k_spmm_bf<<<gs2, 256, 0, stream>>>(C2(2), C2(3), C2(1), off_f, ed_f, N);
    k_spmm4_gemm<<<gg, 256, 0, stream>>>(C2(3), C2(2), off_f, ed_f, TxAll2, BpF,
                                         b21, pooled, 0, batch, N);
    // rev
    k_spmm_bf<<<gs2, 256, 0, stream>>>(C2(0), C2(1), nullptr, off_r, ed_r, N);
    k_spmm_bf<<<gs2, 256, 0, stream>>>(C2(1), C2(2), C2(0), off_r, ed_r, N);
    k_spmm_bf<<<gs2, 256, 0, stream>>>(C2(2), C2(3), C2(1), off_r, ed_r, N);
    k_spmm4_gemm<<<gg, 256, 0, stream>>>(C2(3), C2(2), off_r, ed_r, TxAll2, BpR,
                                         b22, pooled, 256, batch, N);

    k_logits<<<NGRAPH, 64, 0, stream>>>(pooled, gstart, fcw, fcb, out);
}

// Round 8
// 738.352 us; speedup vs baseline: 1.1577x; 1.1577x over previous
//
#include <hip/hip_runtime.h>
#include <stdint.h>

#define NGRAPH 256
#define KCH 5
#define F1 16
#define O1 64
#define F2 128
#define O2 256
#define FT1 (KCH * F1) /* 80 */
#define FT2 (KCH * F2) /* 640: K extent of layer-2 GEMM */
#define STRH 128       /* h buffer stride (ushorts) */
#define STRC 512       /* chunk buffer stride (ushorts): T1..T4 */
#define KSTEPS 20      /* 640/32 */
#define KS1 3          /* ceil(80/32) */
#define LROW 40        /* GEMM LDS staging row stride in ushorts */
#define NXCD 8

typedef unsigned short ushort_t;
typedef __attribute__((ext_vector_type(8))) short bf16x8;
typedef __attribute__((ext_vector_type(4))) float f32x4;

__device__ __forceinline__ float bflo(unsigned int u) {
    union { unsigned int u; float f; } v; v.u = u << 16; return v.f;
}
__device__ __forceinline__ float bfhi(unsigned int u) {
    union { unsigned int u; float f; } v; v.u = u & 0xFFFF0000u; return v.f;
}
__device__ __forceinline__ unsigned int f2bf(float f) {
    union { float f; unsigned int u; } v; v.f = f;
    return (v.u + 0x7FFFu + ((v.u >> 16) & 1u)) >> 16;  // RNE
}
__device__ __forceinline__ unsigned int pack2(float lo, float hi) {
    return (f2bf(hi) << 16) | f2bf(lo);
}

// -------------------- CSR build --------------------

__global__ void k_count(const int* __restrict__ src, const int* __restrict__ dst,
                        int* __restrict__ cntDst, int* __restrict__ cntSrc, int E) {
    int e = blockIdx.x * 256 + threadIdx.x;
    if (e < E) {
        atomicAdd(&cntDst[dst[e]], 1);
        atomicAdd(&cntSrc[src[e]], 1);
    }
}

__global__ void k_dinv(const int* __restrict__ cntDst, const int* __restrict__ cntSrc,
                       float* __restrict__ dinvF, float* __restrict__ dinvR, int n) {
    int i = blockIdx.x * 256 + threadIdx.x;
    if (i < n) {
        int cs = cntSrc[i], cd = cntDst[i];
        dinvF[i] = cs > 0 ? rsqrtf((float)cs) : 0.f;
        dinvR[i] = cd > 0 ? rsqrtf((float)cd) : 0.f;
    }
}

// merged exclusive scans (fwd+rev in one launch), 512 elems/block-half
__global__ void k_scan1m(const int* __restrict__ inF, int* __restrict__ outF,
                         int* __restrict__ bsF,
                         const int* __restrict__ inR, int* __restrict__ outR,
                         int* __restrict__ bsR, int n, int NB) {
    __shared__ int a[512];
    __shared__ int s[256];
    int b = blockIdx.x;
    const int* in; int* out; int* bs; int lb;
    if (b < NB) { in = inF; out = outF; bs = bsF; lb = b; }
    else        { in = inR; out = outR; bs = bsR; lb = b - NB; }
    int t = threadIdx.x;
    int base = lb * 512;
    a[t]       = (base + t < n)       ? in[base + t]       : 0;
    a[t + 256] = (base + t + 256 < n) ? in[base + t + 256] : 0;
    __syncthreads();
    s[t] = a[2 * t] + a[2 * t + 1];
    __syncthreads();
    for (int off = 1; off < 256; off <<= 1) {
        int v = (t >= off) ? s[t - off] : 0;
        __syncthreads();
        s[t] += v;
        __syncthreads();
    }
    int ep = (t > 0) ? s[t - 1] : 0;
    if (base + 2 * t < n)     out[base + 2 * t]     = ep;
    if (base + 2 * t + 1 < n) out[base + 2 * t + 1] = ep + a[2 * t];
    if (t == 255) bs[lb] = s[255];
}

__global__ void k_scan2m(int* __restrict__ bsF, int* __restrict__ bsR, int nb) {
    __shared__ int s[256];
    int* bs = (blockIdx.x == 0) ? bsF : bsR;
    int t = threadIdx.x;
    s[t] = (t < nb) ? bs[t] : 0;
    __syncthreads();
    for (int off = 1; off < 256; off <<= 1) {
        int v = (t >= off) ? s[t - off] : 0;
        __syncthreads();
        s[t] += v;
        __syncthreads();
    }
    if (t < nb) bs[t] = (t > 0) ? s[t - 1] : 0;
}

// adds block prefix, mirrors into cur, writes off[n]=E tail
__global__ void k_scan3m(int* __restrict__ outF, int* __restrict__ curF,
                         const int* __restrict__ bsF,
                         int* __restrict__ outR, int* __restrict__ curR,
                         const int* __restrict__ bsR, int n, int E, int NB) {
    int b = blockIdx.x;
    int* out; int* cur; const int* bs; int lb;
    if (b < NB) { out = outF; cur = curF; bs = bsF; lb = b; }
    else        { out = outR; cur = curR; bs = bsR; lb = b - NB; }
    int i = lb * 512 + threadIdx.x;
    int add = bs[lb];
    if (i < n)       { int v = out[i] + add;       out[i] = v;       cur[i] = v; }
    if (i + 256 < n) { int v = out[i + 256] + add; out[i + 256] = v; cur[i + 256] = v; }
    if (lb == 0 && threadIdx.x == 0) out[n] = E;
}

// XCD-localized scatter (verified r1: kills 8x write amplification)
__global__ void k_scatter(const int* __restrict__ src, const int* __restrict__ dst,
                          const float* __restrict__ dinvF, const float* __restrict__ dinvR,
                          int* __restrict__ curF, int* __restrict__ curR,
                          int2* __restrict__ edF, int2* __restrict__ edR, int E,
                          int chunk) {
    int c = blockIdx.x & (NXCD - 1);
    int sb = blockIdx.x >> 3;
    int slices = gridDim.x >> 3;
    int lo = c * chunk, hi = lo + chunk;
    for (int e = sb * 256 + threadIdx.x; e < E; e += slices * 256) {
        int s = src[e], d = dst[e];
        if (d >= lo && d < hi) {
            int p = atomicAdd(&curF[d], 1);
            float wf = -dinvF[s] * dinvF[d];
            edF[p] = make_int2(s, __float_as_int(wf));
        }
        if (s >= lo && s < hi) {
            int q = atomicAdd(&curR[s], 1);
            float wr = -dinvR[s] * dinvR[d];
            edR[q] = make_int2(d, __float_as_int(wr));
        }
    }
}

__global__ void k_gstart(const int* __restrict__ batch, int* __restrict__ gstart, int n) {
    int g = blockIdx.x * 64 + threadIdx.x;
    if (g > NGRAPH) return;
    if (g == NGRAPH) { gstart[g] = n; return; }
    int lo = 0, hi = n;
    while (lo < hi) {
        int mid = (lo + hi) >> 1;
        if (batch[mid] < g) lo = mid + 1; else hi = mid;
    }
    gstart[g] = lo;
}

// -------------------- compute --------------------

// copy x into chunk 0 of Tx1F (and Tx1R when dual)
__global__ void k_copyx(const float* __restrict__ x, float* __restrict__ TxF,
                        float* __restrict__ TxR, int n) {
    int tid = blockIdx.x * 256 + threadIdx.x;
    int r = tid >> 2, c = tid & 3;
    if (r < n) {
        float4 v = *(const float4*)(x + (size_t)r * 16 + c * 4);
        *(float4*)(TxF + (size_t)r * FT1 + c * 4) = v;
        if (TxR) *(float4*)(TxR + (size_t)r * FT1 + c * 4) = v;
    }
}

// DUAL fp32 SpMM (layer 1): fwd half (b<half) / rev half in one launch.
// half=gridDim -> pure fwd; half=0 -> pure rev (serial fallback path).
// Body = r1-proven loop.
__global__ void k_spmm_f32d(const float* __restrict__ HinF, float* __restrict__ HoutF,
                            const float* __restrict__ Tx0F,
                            const float* __restrict__ HinR, float* __restrict__ HoutR,
                            const float* __restrict__ Tx0R,
                            const int* __restrict__ offF, const int2* __restrict__ edF,
                            const int* __restrict__ offR, const int2* __restrict__ edR,
                            int n, int half) {
    int b = blockIdx.x;
    const float* Hin; float* Hout; const float* Tx0;
    const int* off; const int2* ed; int lb;
    if (b < half) { Hin = HinF; Hout = HoutF; Tx0 = Tx0F; off = offF; ed = edF; lb = b; }
    else          { Hin = HinR; Hout = HoutR; Tx0 = Tx0R; off = offR; ed = edR; lb = b - half; }
    int tid = lb * 256 + threadIdx.x;
    int r = tid >> 2, c = tid & 3;
    if (r >= n) return;
    int j0 = off[r], j1 = off[r + 1];
    float4 s = {0.f, 0.f, 0.f, 0.f};
    int j = j0;
    for (; j + 4 <= j1; j += 4) {
        int2 e0 = ed[j], e1 = ed[j + 1], e2 = ed[j + 2], e3 = ed[j + 3];
        float wa = __int_as_float(e0.y), wb = __int_as_float(e1.y);
        float wc = __int_as_float(e2.y), wd = __int_as_float(e3.y);
        const float4 h0 = *(const float4*)(Hin + (size_t)e0.x * FT1 + c * 4);
        const float4 h1 = *(const float4*)(Hin + (size_t)e1.x * FT1 + c * 4);
        const float4 h2 = *(const float4*)(Hin + (size_t)e2.x * FT1 + c * 4);
        const float4 h3 = *(const float4*)(Hin + (size_t)e3.x * FT1 + c * 4);
        s.x += wa * h0.x; s.y += wa * h0.y; s.z += wa * h0.z; s.w += wa * h0.w;
        s.x += wb * h1.x; s.y += wb * h1.y; s.z += wb * h1.z; s.w += wb * h1.w;
        s.x += wc * h2.x; s.y += wc * h2.y; s.z += wc * h2.z; s.w += wc * h2.w;
        s.x += wd * h3.x; s.y += wd * h3.y; s.z += wd * h3.z; s.w += wd * h3.w;
    }
    for (; j < j1; ++j) {
        int2 e = ed[j];
        float w2 = __int_as_float(e.y);
        const float4 h = *(const float4*)(Hin + (size_t)e.x * FT1 + c * 4);
        s.x += w2 * h.x; s.y += w2 * h.y; s.z += w2 * h.z; s.w += w2 * h.w;
    }
    float4 o;
    if (Tx0) {
        const float4 t0 = *(const float4*)(Tx0 + (size_t)r * FT1 + c * 4);
        o.x = 2.f * s.x - t0.x; o.y = 2.f * s.y - t0.y;
        o.z = 2.f * s.z - t0.z; o.w = 2.f * s.w - t0.w;
    } else {
        o = s;
    }
    *(float4*)(Hout + (size_t)r * FT1 + c * 4) = o;
}

// DUAL bf16 SpMM (layer 2): r1-proven body; explicit strides so sources can
// be the h buffer (stride 128) or chunk buffer (stride 512).
__global__ void k_spmm_bfd(const ushort_t* __restrict__ HinF, ushort_t* __restrict__ HoutF,
                           const ushort_t* __restrict__ Tx0F,
                           const ushort_t* __restrict__ HinR, ushort_t* __restrict__ HoutR,
                           const ushort_t* __restrict__ Tx0R,
                           int strIn, int strOut, int strT0,
                           const int* __restrict__ offF, const int2* __restrict__ edF,
                           const int* __restrict__ offR, const int2* __restrict__ edR,
                           int n, int half) {
    int b = blockIdx.x;
    const ushort_t* Hin; ushort_t* Hout; const ushort_t* Tx0;
    const int* off; const int2* ed; int lb;
    if (b < half) { Hin = HinF; Hout = HoutF; Tx0 = Tx0F; off = offF; ed = edF; lb = b; }
    else          { Hin = HinR; Hout = HoutR; Tx0 = Tx0R; off = offR; ed = edR; lb = b - half; }
    int r = lb * 4 + (threadIdx.x >> 6);
    r = __builtin_amdgcn_readfirstlane(r);
    int c = threadIdx.x & 63;
    if (r >= n) return;
    int j0 = __builtin_amdgcn_readfirstlane(off[r]);
    int j1 = __builtin_amdgcn_readfirstlane(off[r + 1]);
    float s0 = 0.f, s1 = 0.f;
    int j = j0;
    int jfull = j0 + ((j1 - j0) & ~7);
    for (; j < jfull; j += 8) {
        float w[8];
        unsigned int h[8];
#pragma unroll
        for (int sl = 0; sl < 8; ++sl) {
            int2 e = ed[j + sl];
            w[sl] = __int_as_float(e.y);
            h[sl] = *(const unsigned int*)(Hin + (size_t)e.x * strIn + c * 2);
        }
#pragma unroll
        for (int sl = 0; sl < 8; ++sl) {
            s0 = fmaf(bflo(h[sl]), w[sl], s0);
            s1 = fmaf(bfhi(h[sl]), w[sl], s1);
        }
    }
    int rem = j1 - j;  // wave-uniform
    if (rem) {
        float w[8];
        unsigned int h[8];
#pragma unroll
        for (int sl = 0; sl < 8; ++sl) {
            w[sl] = 0.f; h[sl] = 0u;
            if (sl < rem) {  // uniform branch
                int2 e = ed[j + sl];
                w[sl] = __int_as_float(e.y);
                h[sl] = *(const unsigned int*)(Hin + (size_t)e.x * strIn + c * 2);
            }
        }
#pragma unroll
        for (int sl = 0; sl < 8; ++sl) {
            s0 = fmaf(bflo(h[sl]), w[sl], s0);
            s1 = fmaf(bfhi(h[sl]), w[sl], s1);
        }
    }
    if (Tx0) {
        unsigned int t0 = *(const unsigned int*)(Tx0 + (size_t)r * strT0 + c * 2);
        s0 = 2.f * s0 - bflo(t0);
        s1 = 2.f * s1 - bfhi(t0);
    }
    *(unsigned int*)(Hout + (size_t)r * strOut + c * 2) = pack2(s0, s1);
}

// merged pack W [80,64] -> bf16 MFMA B-frags (both directions), K 80->96
__global__ void k_packW1m(const float* __restrict__ WF, ushort_t* __restrict__ BpF_,
                          const float* __restrict__ WR, ushort_t* __restrict__ BpR_) {
    int b = blockIdx.x;
    const float* W = (b < 3) ? WF : WR;
    ushort_t* Bp = (b < 3) ? BpF_ : BpR_;
    int tid = ((b < 3) ? b : b - 3) * 256 + threadIdx.x;
    if (tid >= 4 * KS1 * 64) return;
    int lane = tid & 63;
    int ks = (tid >> 6) % KS1;
    int nt = tid / (64 * KS1);
    int k0 = ks * 32 + (lane >> 4) * 8;
    int ncol = nt * 16 + (lane & 15);
    float v[8];
#pragma unroll
    for (int j = 0; j < 8; ++j) {
        int k = k0 + j;
        v[j] = (k < FT1) ? W[(size_t)k * O1 + ncol] : 0.f;
    }
    uint4 o;
    o.x = pack2(v[0], v[1]); o.y = pack2(v[2], v[3]);
    o.z = pack2(v[4], v[5]); o.w = pack2(v[6], v[7]);
    *(uint4*)(Bp + (size_t)tid * 8) = o;
}

// DUAL layer-1 MFMA GEMM: writes h into shared H buffer (fwd cols 0-63,
// rev cols 64-127). half=grid -> all fwd; half=0 -> all rev.
__global__ __launch_bounds__(256) void k_gemm1d(
    const float* __restrict__ AF, const ushort_t* __restrict__ BpF_,
    const float* __restrict__ bF,
    const float* __restrict__ AR, const ushort_t* __restrict__ BpR_,
    const float* __restrict__ bR,
    ushort_t* __restrict__ H, int n, int half) {
    int b = blockIdx.x;
    const float* A; const ushort_t* Bp; const float* bias; int colb; int lb;
    if (b < half) { A = AF; Bp = BpF_; bias = bF; colb = 0;  lb = b; }
    else          { A = AR; Bp = BpR_; bias = bR; colb = O1; lb = b - half; }
    int lane = threadIdx.x & 63;
    int wvi = threadIdx.x >> 6;
    int mrow = lane & 15;
    int quad = lane >> 4;
    int m0w = lb * 64 + wvi * 16;
    int row = m0w + mrow;
    int rowc = row < n ? row : n - 1;
    const float* Ar = A + (size_t)rowc * FT1 + quad * 8;

    f32x4 acc[4] = {};
#pragma unroll
    for (int ks = 0; ks < KS1; ++ks) {
        float4 a0 = *(const float4*)(Ar + ks * 32);
        float4 a1 = *(const float4*)(Ar + ks * 32 + 4);
        union { bf16x8 v; unsigned int u[4]; } ua;
        ua.u[0] = pack2(a0.x, a0.y);
        ua.u[1] = pack2(a0.z, a0.w);
        ua.u[2] = pack2(a1.x, a1.y);
        ua.u[3] = pack2(a1.z, a1.w);
#pragma unroll
        for (int nf = 0; nf < 4; ++nf) {
            bf16x8 bfr = *(const bf16x8*)(Bp + ((size_t)(nf * KS1 + ks) * 64 + lane) * 8);
            acc[nf] = __builtin_amdgcn_mfma_f32_16x16x32_bf16(ua.v, bfr, acc[nf], 0, 0, 0);
        }
    }
#pragma unroll
    for (int nf = 0; nf < 4; ++nf) {
        float bb = bias[nf * 16 + mrow];
#pragma unroll
        for (int reg = 0; reg < 4; ++reg) {
            int orow = m0w + quad * 4 + reg;
            if (orow < n)
                H[(size_t)orow * STRH + colb + nf * 16 + mrow] =
                    (ushort_t)f2bf(fmaxf(acc[nf][reg] + bb, 0.f));
        }
    }
}

// merged pack W [640,256] -> bf16 MFMA B-fragment layout (both directions)
__global__ void k_packWm(const float* __restrict__ WF, ushort_t* __restrict__ BpF_,
                         const float* __restrict__ WR, ushort_t* __restrict__ BpR_) {
    int b = blockIdx.x;
    const float* W = (b < 80) ? WF : WR;
    ushort_t* Bp = (b < 80) ? BpF_ : BpR_;
    int tid = ((b < 80) ? b : b - 80) * 256 + threadIdx.x;
    if (tid >= 16 * KSTEPS * 64) return;
    int lane = tid & 63;
    int ks = (tid >> 6) % KSTEPS;
    int nt = tid / (64 * KSTEPS);
    int k0 = ks * 32 + (lane >> 4) * 8;
    int ncol = nt * 16 + (lane & 15);
    float v[8];
#pragma unroll
    for (int j = 0; j < 8; ++j) v[j] = W[(size_t)(k0 + j) * O2 + ncol];
    uint4 o;
    o.x = pack2(v[0], v[1]); o.y = pack2(v[2], v[3]);
    o.z = pack2(v[4], v[5]); o.w = pack2(v[6], v[7]);
    *(uint4*)(Bp + (size_t)tid * 8) = o;
}

// DUAL layer-2 MFMA GEMM, r1-proven body with two-source A staging:
// K-steps 0..3 read from the shared h buffer (stride 128), 4..19 from the
// per-direction chunk buffer (stride 512).
__global__ __launch_bounds__(256) void k_gemm2d(
    const ushort_t* __restrict__ H,
    const ushort_t* __restrict__ CFp, const ushort_t* __restrict__ BpF_,
    const float* __restrict__ bF,
    const ushort_t* __restrict__ CRp, const ushort_t* __restrict__ BpR_,
    const float* __restrict__ bR,
    float* __restrict__ pooled, const int* __restrict__ batch, int n, int half) {
    __shared__ ushort_t lds[2][64 * LROW];  // 2 x 5120 B

    int b = blockIdx.x;
    const ushort_t* C; const ushort_t* Bp; const float* bias; int colofs; int lb;
    if (b < half) { C = CFp; Bp = BpF_; bias = bF; colofs = 0;   lb = b; }
    else          { C = CRp; Bp = BpR_; bias = bR; colofs = 256; lb = b - half; }

    int lane = threadIdx.x & 63;
    int wv = threadIdx.x >> 6;
    int m0 = lb * 64;
    int mrow = lane & 15;
    int quad = lane >> 4;
    int srow = threadIdx.x >> 2;
    int sc = threadIdx.x & 3;

    const ushort_t* AgH = H + (size_t)(m0 + srow) * STRH + sc * 8;
    const ushort_t* AgC = C + (size_t)(m0 + srow) * STRC + sc * 8;
    const ushort_t* Bbase = Bp + ((size_t)(wv * 4) * KSTEPS * 64 + lane) * 8;
    int sidx = srow * LROW + sc * 8;

    f32x4 acc[4][4] = {};
    uint4 nxt;
    bf16x8 bcur[4], bnxt[4];

    auto aload = [&](int ks) {
        return (ks < 4) ? *(const uint4*)(AgH + ks * 32)
                        : *(const uint4*)(AgC + (ks - 4) * 32);
    };

    // prologue: A stage 0 -> buf0; A stage 1 in regs; B stage 0 in regs
    *(uint4*)&lds[0][sidx] = aload(0);
    nxt = aload(1);
#pragma unroll
    for (int nf = 0; nf < 4; ++nf)
        bcur[nf] = *(const bf16x8*)(Bbase + ((size_t)nf * KSTEPS) * 512);

    for (int ks = 0; ks < KSTEPS; ++ks) {
        __syncthreads();
        if (ks + 1 < KSTEPS)
            *(uint4*)&lds[(ks + 1) & 1][sidx] = nxt;
        if (ks + 2 < KSTEPS)
            nxt = aload(ks + 2);
        if (ks + 1 < KSTEPS) {
#pragma unroll
            for (int nf = 0; nf < 4; ++nf)
                bnxt[nf] = *(const bf16x8*)(Bbase + ((size_t)nf * KSTEPS + ks + 1) * 512);
        }
        bf16x8 af[4];
        const ushort_t* lbuf = &lds[ks & 1][0];
#pragma unroll
        for (int mf = 0; mf < 4; ++mf)
            af[mf] = *(const bf16x8*)(lbuf + (mf * 16 + mrow) * LROW + quad * 8);
#pragma unroll
        for (int mf = 0; mf < 4; ++mf)
#pragma unroll
            for (int nf = 0; nf < 4; ++nf)
                acc[mf][nf] = __builtin_amdgcn_mfma_f32_16x16x32_bf16(
                    af[mf], bcur[nf], acc[mf][nf], 0, 0, 0);
#pragma unroll
        for (int nf = 0; nf < 4; ++nf) bcur[nf] = bnxt[nf];
    }

    // epilogue: pool into pooled[g*512 + colofs + col]
    float bcol[4];
#pragma unroll
    for (int nf = 0; nf < 4; ++nf) bcol[nf] = bias[wv * 64 + nf * 16 + mrow];

#pragma unroll
    for (int mf = 0; mf < 4; ++mf) {
        int t0 = m0 + mf * 16;
        if (t0 >= n) break;
        int te = (t0 + 15 < n) ? t0 + 15 : n - 1;
        int r0 = t0 + quad * 4;
        if (batch[t0] == batch[te]) {
            int g = batch[t0];
#pragma unroll
            for (int nf = 0; nf < 4; ++nf) {
                float s = 0.f;
#pragma unroll
                for (int reg = 0; reg < 4; ++reg) {
                    float v = fmaxf(acc[mf][nf][reg] + bcol[nf], 0.f);
                    if (r0 + reg < n) s += v;
                }
                s += __shfl_xor(s, 16, 64);
                s += __shfl_xor(s, 32, 64);
                if (quad == 0)
                    atomicAdd(pooled + (size_t)g * 512 + colofs + wv * 64 + nf * 16 + mrow, s);
            }
        } else {
            int gb[4];
#pragma unroll
            for (int reg = 0; reg < 4; ++reg)
                gb[reg] = batch[(r0 + reg < n) ? r0 + reg : n - 1];
#pragma unroll
            for (int nf = 0; nf < 4; ++nf) {
                int col = colofs + wv * 64 + nf * 16 + mrow;
                float run = 0.f;
                int g = gb[0];
                bool any = false;
#pragma unroll
                for (int reg = 0; reg < 4; ++reg) {
                    int row = r0 + reg;
                    if (row >= n) break;
                    float v = fmaxf(acc[mf][nf][reg] + bcol[nf], 0.f);
                    if (gb[reg] != g) {
                        atomicAdd(pooled + (size_t)g * 512 + col, run);
                        run = 0.f;
                        g = gb[reg];
                    }
                    run += v;
                    any = true;
                }
                if (any) atomicAdd(pooled + (size_t)g * 512 + col, run);
            }
        }
    }
}

// parallel logits: one block (64 threads) per graph
__global__ void k_logits(const float* __restrict__ pooled, const int* __restrict__ gstart,
                         const float* __restrict__ fcw, const float* __restrict__ fcb,
                         float* __restrict__ out) {
    int g = blockIdx.x;
    int l = threadIdx.x;
    int cnt = gstart[g + 1] - gstart[g];
    float inv = 1.f / (float)(cnt > 1 ? cnt : 1);
    float lg0 = 0.f, lg1 = 0.f, lg2 = 0.f, lg3 = 0.f;
    for (int f = l; f < 512; f += 64) {
        float p = pooled[g * 512 + f] * inv;
        const float4 wv4 = *(const float4*)(fcw + f * 4);
        lg0 = fmaf(p, wv4.x, lg0);
        lg1 = fmaf(p, wv4.y, lg1);
        lg2 = fmaf(p, wv4.z, lg2);
        lg3 = fmaf(p, wv4.w, lg3);
    }
#pragma unroll
    for (int o = 32; o > 0; o >>= 1) {
        lg0 += __shfl_down(lg0, o, 64);
        lg1 += __shfl_down(lg1, o, 64);
        lg2 += __shfl_down(lg2, o, 64);
        lg3 += __shfl_down(lg3, o, 64);
    }
    if (l == 0) {
        float lg[4] = {lg0 + fcb[0], lg1 + fcb[1], lg2 + fcb[2], lg3 + fcb[3]};
        float m = fmaxf(fmaxf(lg[0], lg[1]), fmaxf(lg[2], lg[3]));
        float s = 0.f;
#pragma unroll
        for (int o = 0; o < 4; ++o) s += expf(lg[o] - m);
        float lsum = logf(s);
#pragma unroll
        for (int o = 0; o < 4; ++o) out[g * 4 + o] = lg[o] - m - lsum;
    }
}

// -------------------- launch --------------------

extern "C" void kernel_launch(void* const* d_in, const int* in_sizes, int n_in,
                              void* d_out, int out_size, void* d_ws, size_t ws_size,
                              hipStream_t stream) {
    const float* x   = (const float*)d_in[0];
    const int* ei    = (const int*)d_in[1];
    const int* batch = (const int*)d_in[2];
    const float* W11 = (const float*)d_in[3];
    const float* b11 = (const float*)d_in[4];
    const float* W12 = (const float*)d_in[5];
    const float* b12 = (const float*)d_in[6];
    const float* W21 = (const float*)d_in[7];
    const float* b21 = (const float*)d_in[8];
    const float* W22 = (const float*)d_in[9];
    const float* b22 = (const float*)d_in[10];
    const float* fcw = (const float*)d_in[11];
    const float* fcb = (const float*)d_in[12];
    float* out = (float*)d_out;

    const int N = in_sizes[0] / F1;
    const int E = in_sizes[1] / 2;
    const int* src = ei;
    const int* dst = ei + E;

    char* w = (char*)d_ws;
    size_t pos = 0;
    auto alloc = [&](size_t bytes) -> void* {
        void* p = w + pos;
        pos += (bytes + 255) & ~(size_t)255;
        return p;
    };
    int* cur_f   = (int*)alloc((size_t)N * 4);
    int* cur_r   = (int*)alloc((size_t)N * 4);
    int* off_f   = (int*)alloc((size_t)(N + 1) * 4);
    int* off_r   = (int*)alloc((size_t)(N + 1) * 4);
    float* dinvF = (float*)alloc((size_t)N * 4);
    float* dinvR = (float*)alloc((size_t)N * 4);
    int2* ed_f   = (int2*)alloc((size_t)E * 8);
    int2* ed_r   = (int2*)alloc((size_t)E * 8);
    int* blks_f  = (int*)alloc(1024);
    int* blks_r  = (int*)alloc(1024);
    int* gstart  = (int*)alloc((NGRAPH + 1) * 4);
    float* pooled = (float*)alloc((size_t)NGRAPH * 512 * 4);
    ushort_t* BpF = (ushort_t*)alloc((size_t)FT2 * O2 * 2);
    ushort_t* BpR = (ushort_t*)alloc((size_t)FT2 * O2 * 2);
    ushort_t* Bp1F = (ushort_t*)alloc((size_t)4 * KS1 * 64 * 8 * 2);
    ushort_t* Bp1R = (ushort_t*)alloc((size_t)4 * KS1 * 64 * 8 * 2);
    // shared h buffer [N+64, 128] bf16 (chunk 0 for BOTH directions)
    ushort_t* H  = (ushort_t*)alloc((size_t)(N + 64) * STRH * 2);   // 25.6 MB
    // fwd chunk buffer T1..T4 [N+64, 512] bf16
    ushort_t* CF = (ushort_t*)alloc((size_t)(N + 64) * STRC * 2);   // 102.5 MB
    // layer-1 fp32 state, fwd
    float* Tx1F = (float*)alloc(((size_t)N * FT1 + 256) * 4);       // 32.1 MB
    size_t serialNeed = pos;                                        // ~177 MB
    // dual extras: Tx1R + pad so that CR (aliasing Tx1F..) spans a full chunk buffer.
    // Tx1F/Tx1R are DEAD after gemm1d; CR's first write (layer-2 step 1) comes after.
    size_t crOff = (size_t)((char*)Tx1F - w);
    size_t crBytes = (size_t)(N + 64) * STRC * 2;
    float* Tx1R = (float*)alloc(((size_t)N * FT1 + 256) * 4);       // 32.1 MB
    if (pos < crOff + crBytes) pos = crOff + crBytes;
    size_t dualNeed = pos;                                          // ~247 MB
    bool dual = (ws_size >= dualNeed) && (ws_size >= serialNeed);
    ushort_t* CR = dual ? (ushort_t*)(w + crOff) : CF;
    if (!dual) Tx1R = Tx1F;  // unused distinctly in serial path

    (void)hipMemsetAsync(cur_f, 0, (size_t)N * 4, stream);
    (void)hipMemsetAsync(cur_r, 0, (size_t)N * 4, stream);
    (void)hipMemsetAsync(pooled, 0, (size_t)NGRAPH * 512 * 4, stream);

    int gE = (E + 255) / 256, gN = (N + 255) / 256;
    k_count<<<gE, 256, 0, stream>>>(src, dst, cur_f, cur_r, E);
    k_dinv<<<gN, 256, 0, stream>>>(cur_f, cur_r, dinvF, dinvR, N);

    int NB = (N + 511) / 512;
    k_scan1m<<<2 * NB, 256, 0, stream>>>(cur_f, off_f, blks_f, cur_r, off_r, blks_r, N, NB);
    k_scan2m<<<2, 256, 0, stream>>>(blks_f, blks_r, NB);
    k_scan3m<<<2 * NB, 256, 0, stream>>>(off_f, cur_f, blks_f, off_r, cur_r, blks_r, N, E, NB);
    int chunk = (N + NXCD - 1) / NXCD;
    k_scatter<<<NXCD * 256, 256, 0, stream>>>(src, dst, dinvF, dinvR, cur_f, cur_r,
                                              ed_f, ed_r, E, chunk);
    k_gstart<<<5, 64, 0, stream>>>(batch, gstart, N);
    k_packWm<<<160, 256, 0, stream>>>(W21, BpF, W22, BpR);
    k_packW1m<<<6, 256, 0, stream>>>(W11, Bp1F, W12, Bp1R);

    int gs1 = (N * 4 + 255) / 256;
    int gg1 = (N + 63) / 64;
    int gs2 = (N + 3) / 4;
    int gg = (N + 63) / 64;
    auto CFc = [&](int k) { return Tx1F + k * F1; };
    auto CRc = [&](int k) { return Tx1R + k * F1; };
    // layer-2 chunk t (1..4) lives at col (t-1)*128 of the chunk buffer
    auto CT = [&](ushort_t* C, int t) { return C + (t - 1) * F2; };

    if (dual) {
        // ---- layer 1, fwd+rev concurrent ----
        k_copyx<<<(N * 4 + 255) / 256, 256, 0, stream>>>(x, Tx1F, Tx1R, N);
        k_spmm_f32d<<<2 * gs1, 256, 0, stream>>>(CFc(0), CFc(1), nullptr,
                                                 CRc(0), CRc(1), nullptr,
                                                 off_f, ed_f, off_r, ed_r, N, gs1);
        k_spmm_f32d<<<2 * gs1, 256, 0, stream>>>(CFc(1), CFc(2), CFc(0),
                                                 CRc(1), CRc(2), CRc(0),
                                                 off_f, ed_f, off_r, ed_r, N, gs1);
        k_spmm_f32d<<<2 * gs1, 256, 0, stream>>>(CFc(2), CFc(3), CFc(1),
                                                 CRc(2), CRc(3), CRc(1),
                                                 off_f, ed_f, off_r, ed_r, N, gs1);
        k_spmm_f32d<<<2 * gs1, 256, 0, stream>>>(CFc(3), CFc(4), CFc(2),
                                                 CRc(3), CRc(4), CRc(2),
                                                 off_f, ed_f, off_r, ed_r, N, gs1);
        k_gemm1d<<<2 * gg1, 256, 0, stream>>>(Tx1F, Bp1F, b11, Tx1R, Bp1R, b12,
                                              H, N, gg1);
        // ---- layer 2, fwd+rev concurrent (Tx1 dead; CR alias live now) ----
        k_spmm_bfd<<<2 * gs2, 256, 0, stream>>>(H, CT(CF, 1), nullptr,
                                                H, CT(CR, 1), nullptr,
                                                STRH, STRC, 0,
                                                off_f, ed_f, off_r, ed_r, N, gs2);
        k_spmm_bfd<<<2 * gs2, 256, 0, stream>>>(CT(CF, 1), CT(CF, 2), H,
                                                CT(CR, 1), CT(CR, 2), H,
                                                STRC, STRC, STRH,
                                                off_f, ed_f, off_r, ed_r, N, gs2);
        k_spmm_bfd<<<2 * gs2, 256, 0, stream>>>(CT(CF, 2), CT(CF, 3), CT(CF, 1),
                                                CT(CR, 2), CT(CR, 3), CT(CR, 1),
                                                STRC, STRC, STRC,
                                                off_f, ed_f, off_r, ed_r, N, gs2);
        k_spmm_bfd<<<2 * gs2, 256, 0, stream>>>(CT(CF, 3), CT(CF, 4), CT(CF, 2),
                                                CT(CR, 3), CT(CR, 4), CT(CR, 2),
                                                STRC, STRC, STRC,
                                                off_f, ed_f, off_r, ed_r, N, gs2);
        k_gemm2d<<<2 * gg, 256, 0, stream>>>(H, CF, BpF, b21, CR, BpR, b22,
                                             pooled, batch, N, gg);
    } else {
        // ---- serial fallback (r1-proven schedule, ~177 MB) ----
        k_copyx<<<(N * 4 + 255) / 256, 256, 0, stream>>>(x, Tx1F, nullptr, N);
        // layer-1 fwd
        k_spmm_f32d<<<gs1, 256, 0, stream>>>(CFc(0), CFc(1), nullptr,
                                             CFc(0), CFc(1), nullptr,
                                             off_f, ed_f, off_f, ed_f, N, gs1);
        k_spmm_f32d<<<gs1, 256, 0, stream>>>(CFc(1), CFc(2), CFc(0),
                                             CFc(1), CFc(2), CFc(0),
                                             off_f, ed_f, off_f, ed_f, N, gs1);
        k_spmm_f32d<<<gs1, 256, 0, stream>>>(CFc(2), CFc(3), CFc(1),
                                             CFc(2), CFc(3), CFc(1),
                                             off_f, ed_f, off_f, ed_f, N, gs1);
        k_spmm_f32d<<<gs1, 256, 0, stream>>>(CFc(3), CFc(4), CFc(2),
                                             CFc(3), CFc(4), CFc(2),
                                             off_f, ed_f, off_f, ed_f, N, gs1);
        k_gemm1d<<<gg1, 256, 0, stream>>>(Tx1F, Bp1F, b11, Tx1F, Bp1R, b12, H, N, gg1);
        // layer-1 rev (reuses Tx1F chunks 1..4; chunk 0 = x preserved); half=0 -> rev branch
        k_spmm_f32d<<<gs1, 256, 0, stream>>>(CFc(0), CFc(1), nullptr,
                                             CFc(0), CFc(1), nullptr,
                                             off_r, ed_r, off_r, ed_r, N, 0);
        k_spmm_f32d<<<gs1, 256, 0, stream>>>(CFc(1), CFc(2), CFc(0),
                                             CFc(1), CFc(2), CFc(0),
                                             off_r, ed_r, off_r, ed_r, N, 0);
        k_spmm_f32d<<<gs1, 256, 0, stream>>>(CFc(2), CFc(3), CFc(1),
                                             CFc(2), CFc(3), CFc(1),
                                             off_r, ed_r, off_r, ed_r, N, 0);
        k_spmm_f32d<<<gs1, 256, 0, stream>>>(CFc(3), CFc(4), CFc(2),
                                             CFc(3), CFc(4), CFc(2),
                                             off_r, ed_r, off_r, ed_r, N, 0);
        k_gemm1d<<<gg1, 256, 0, stream>>>(Tx1F, Bp1F, b11, Tx1F, Bp1R, b12, H, N, 0);
        // layer-2 fwd into CF
        k_spmm_bfd<<<gs2, 256, 0, stream>>>(H, CT(CF, 1), nullptr, H, CT(CF, 1), nullptr,
                                            STRH, STRC, 0,
                                            off_f, ed_f, off_f, ed_f, N, gs2);
        k_spmm_bfd<<<gs2, 256, 0, stream>>>(CT(CF, 1), CT(CF, 2), H,
                                            CT(CF, 1), CT(CF, 2), H,
                                            STRC, STRC, STRH,
                                            off_f, ed_f, off_f, ed_f, N, gs2);
        k_spmm_bfd<<<gs2, 256, 0, stream>>>(CT(CF, 2), CT(CF, 3), CT(CF, 1),
                                            CT(CF, 2), CT(CF, 3), CT(CF, 1),
                                            STRC, STRC, STRC,
                                            off_f, ed_f, off_f, ed_f, N, gs2);
        k_spmm_bfd<<<gs2, 256, 0, stream>>>(CT(CF, 3), CT(CF, 4), CT(CF, 2),
                                            CT(CF, 3), CT(CF, 4), CT(CF, 2),
                                            STRC, STRC, STRC,
                                            off_f, ed_f, off_f, ed_f, N, gs2);
        k_gemm2d<<<gg, 256, 0, stream>>>(H, CF, BpF, b21, CF, BpR, b22,
                                         pooled, batch, N, gg);
        // layer-2 rev reusing CF; half=0 -> rev branch (colofs 256)
        k_spmm_bfd<<<gs2, 256, 0, stream>>>(H, CT(CF, 1), nullptr, H, CT(CF, 1), nullptr,
                                            STRH, STRC, 0,
                                            off_r, ed_r, off_r, ed_r, N, 0);
        k_spmm_bfd<<<gs2, 256, 0, stream>>>(CT(CF, 1), CT(CF, 2), H,
                                            CT(CF, 1), CT(CF, 2), H,
                                            STRC, STRC, STRH,
                                            off_r, ed_r, off_r, ed_r, N, 0);
        k_spmm_bfd<<<gs2, 256, 0, stream>>>(CT(CF, 2), CT(CF, 3), CT(CF, 1),
                                            CT(CF, 2), CT(CF, 3), CT(CF, 1),
                                            STRC, STRC, STRC,
                                            off_r, ed_r, off_r, ed_r, N, 0);
        k_spmm_bfd<<<gs2, 256, 0, stream>>>(CT(CF, 3), CT(CF, 4), CT(CF, 2),
                                            CT(CF, 3), CT(CF, 4), CT(CF, 2),
                                            STRC, STRC, STRC,
                                            off_r, ed_r, off_r, ed_r, N, 0);
        k_gemm2d<<<gg, 256, 0, stream>>>(H, CF, BpF, b21, CF, BpR, b22,
                                         pooled, batch, N, 0);
    }

    k_logits<<<NGRAPH, 64, 0, stream>>>(pooled, gstart, fcw, fcb, out);
}